// Round 5
// baseline (3163.143 us; speedup 1.0000x reference)
//
#include <hip/hip_runtime.h>
#include <math.h>

namespace {

constexpr int B = 512, T = 96, IN = 64, H = 512, G4 = 2048;
constexpr int FN = 32, KC = 544, NPRED = 24, TM1 = T - 1;
constexpr int BH = B * H;

typedef __attribute__((ext_vector_type(8))) short s8v;    // 8 bf16
typedef __attribute__((ext_vector_type(16))) float f16v;  // 32x32 acc

__device__ __forceinline__ float sigf(float x) { return 1.0f / (1.0f + __expf(-x)); }
__device__ __forceinline__ float tanhfast(float x) {
  x = fminf(fmaxf(x, -15.f), 15.f);
  float e = __expf(2.0f * x);
  return (e - 1.0f) / (e + 1.0f);
}
__device__ __forceinline__ unsigned short bf16_rne(float f) {
  unsigned u = __float_as_uint(f);
  u += 0x7fffu + ((u >> 16) & 1u);
  return (unsigned short)(u >> 16);
}
__device__ __forceinline__ void split8(const float4& x, const float4& y, s8v& hi, s8v& lo) {
  float vs[8] = {x.x, x.y, x.z, x.w, y.x, y.y, y.z, y.w};
#pragma unroll
  for (int j = 0; j < 8; ++j) {
    unsigned ub = __float_as_uint(vs[j]);
    hi[j] = (short)(ub >> 16);
    lo[j] = (short)bf16_rne(vs[j] - __uint_as_float(ub & 0xffff0000u));
  }
}

// ---- Kernel 1: xc = relu(x @ Wh^T + bh) + embed[sid], f32 planes [t][b][h] ----
__global__ __launch_bounds__(256) void k_xc(
    const float* __restrict__ x, const int* __restrict__ sid,
    const float* __restrict__ Wh, const float* __restrict__ bh,
    const float* __restrict__ emb, float* __restrict__ planes) {
  constexpr int RWS = 64;
  int gid = blockIdx.x;
  int half = gid & 1;
  int row0 = (gid >> 1) * RWS;
  int tid = threadIdx.x;
  int h = half * 256 + tid;
  __shared__ float sx[RWS][IN];  // 16 KB
  {
    const float4* xsrc = (const float4*)(x + (size_t)row0 * IN);
    float4* sdst = (float4*)(&sx[0][0]);
    for (int i = tid; i < RWS * IN / 4; i += 256) sdst[i] = xsrc[i];
  }
  float4 w[16];
  const float* wr = Wh + (size_t)h * IN;
#pragma unroll
  for (int j = 0; j < 16; ++j) w[j] = *(const float4*)(wr + j * 4);
  float b0 = bh[h];
  const float* ep = emb + h;
  __syncthreads();
#pragma unroll 2
  for (int r = 0; r < RWS; ++r) {
    float a0 = b0, a1 = 0.f, a2 = 0.f, a3 = 0.f;
#pragma unroll
    for (int j = 0; j < 16; ++j) {
      float4 xv = *(const float4*)(&sx[r][j * 4]);
      a0 = fmaf(xv.x, w[j].x, a0);
      a1 = fmaf(xv.y, w[j].y, a1);
      a2 = fmaf(xv.z, w[j].z, a2);
      a3 = fmaf(xv.w, w[j].w, a3);
    }
    float acc = (a0 + a1) + (a2 + a3);
    int row = row0 + r;
    int bb = row / T, t = row % T;
    float v = fmaxf(acc, 0.f) + ep[(size_t)sid[bb] * H];
    planes[((size_t)t * B + bb) * H + h] = v;
  }
}

// ---- Kernel 2: pre-swizzle weights into frag-linear split-bf16 ----
// frag f = ((layer*16+ng)*64 + kt)*4 + nt ; element o = f*512 + lane*8
// frag content: n-row = nt*512 + ng*32 + (lane&31); k = kt*16 + (lane>>5)*8 + j
__global__ __launch_bounds__(256) void k_wswz(
    const float* __restrict__ Wih, const float* __restrict__ Whh,
    short* __restrict__ WFhi, short* __restrict__ WFlo) {
  int g = blockIdx.x * 256 + threadIdx.x;
  int lane = g & 63;
  int fi = g >> 6;  // 0..8191
  int nt = fi & 3, kt = (fi >> 2) & 63, ng = (fi >> 8) & 15, layer = fi >> 12;
  int row = nt * H + ng * 32 + (lane & 31);
  int kk = kt * 16 + (lane >> 5) * 8;
  const float* src = (kk < H) ? (Wih + ((size_t)layer * G4 + row) * H + kk)
                              : (Whh + ((size_t)layer * G4 + row) * H + (kk - H));
  float4 f0 = *(const float4*)src, f1 = *(const float4*)(src + 4);
  s8v hi, lo;
  split8(f0, f1, hi, lo);
  size_t o = (size_t)fi * 512 + lane * 8;
  *(s8v*)(WFhi + o) = hi;
  *(s8v*)(WFlo + o) = lo;
}

// ---- Kernel 3 (v5): TLP-maximized LSTM step ----
// Diagnosis r0-r4: achieved per-CU BW scales with resident waves (r1 moved 2x
// r2's bytes in equal time at 2x waves; per-wave chain ~27 GB/s is latency-
// bound and structure-invariant). So: quadruple TLP vs r2.
// 512 blocks x 512 thr, __launch_bounds__(512,4) -> VGPR<=128, 2 blocks/CU,
// 16 waves/CU = 4/SIMD (was 4/CU). Block = (combo, 32-row half-btile);
// wave = (gate nt, K-half kqh): acc = 16 VGPR, 3-deep 4-load pipeline sets.
// The 4 nt-waves of a K-half issue identical A addresses close in time -> L1
// absorbs the duplication. Multi-launch, plain stores, v2 hF layout
// (kernel-boundary coherence, proven).
__global__ __launch_bounds__(512, 4) void k_step5(
    int tt, float* __restrict__ planes, const short* __restrict__ WFhi,
    const short* __restrict__ WFlo, short* __restrict__ hFhi,
    short* __restrict__ hFlo, const float* __restrict__ bih,
    const float* __restrict__ bhh, float* __restrict__ c0,
    float* __restrict__ c1) {
  int gid = blockIdx.x;
  int xcd = gid & 7;
  int u = gid >> 3;               // 0..63
  int combo = xcd * 4 + (u & 3);  // (layer,ng): 4 W slices (2MB) per XCD L2
  int layer = combo >> 4;
  if (layer ? (tt == 0) : (tt == T)) return;
  int ng = combo & 15;
  int bt2 = u >> 2;  // 0..15: 32-row tile index
  int b0 = bt2 * 32;
  int step = layer ? (tt - 1) : tt;
  int tid = threadIdx.x, lane = tid & 63;
  int wv = tid >> 6;              // 0..7
  int nt = wv & 3, kqh = wv >> 2; // gate, K-half
  int l31 = lane & 31, lh = lane >> 5;

  __shared__ float comb[2][4][32][32];  // [kqh][nt][row][col] 32 KB

  const float* bi = bih + (size_t)layer * G4;
  const float* bh2 = bhh + (size_t)layer * G4;
  float* cbuf = layer ? c1 : c0;

  int rpar = (step - 1) & 1;  // (-1)&1==1: zeroed initial-state buffer
  bool use_x = (layer == 0) && (kqh == 0);
  const float* xbase = nullptr;
  const short *abhi = nullptr, *ablo = nullptr;
  if (use_x) {
    xbase = planes + (size_t)step * BH + (size_t)(b0 + l31) * H + lh * 8;
  } else {
    int src = (layer == 0) ? 0 : ((kqh == 0) ? 0 : 1);
    int par = (layer == 0) ? rpar : ((kqh == 0) ? (step & 1) : rpar);
    size_t o = ((((size_t)src * 2 + par) * 32) * H + (size_t)(b0 + l31)) * 16 + lh * 8;
    abhi = hFhi + o;
    ablo = hFlo + o;
  }

  float bias[4];
#pragma unroll
  for (int q = 0; q < 4; ++q) {
    int r = q * H + ng * 32 + l31;
    bias[q] = bi[r] + bh2[r];
  }

  // W frag for this wave: f = ((layer*16+ng)*64 + kqh*32 + i)*4 + nt
  const size_t wstep = 4 * 512;  // shorts per kt
  const size_t wb = (((size_t)(layer * 16 + ng) * 64 + (size_t)kqh * 32) * 4 + nt) * 512 +
                    (size_t)lane * 8;
  const size_t astep = (size_t)H * 16;  // shorts per kt in hF

  f16v acc;
#pragma unroll
  for (int e = 0; e < 16; ++e) acc[e] = 0.f;

  // statically-named 3-deep pipelined sets (rule #20): {Whi, Wlo, Ahi, Alo}
  s8v w0h, w0l, a0h, a0l;
  s8v w1h, w1l, a1h, a1l;
  s8v w2h, w2l, a2h, a2l;

#define LOADS_(i, wh_, wl_, ah_, al_)                                 \
  {                                                                   \
    size_t wo = wb + (size_t)(i) * wstep;                             \
    wh_ = *(const s8v*)(WFhi + wo);                                   \
    wl_ = *(const s8v*)(WFlo + wo);                                   \
    if (use_x) {                                                      \
      const float* ap = xbase + (i) * 16;                             \
      float4 f0 = *(const float4*)ap, f1 = *(const float4*)(ap + 4);  \
      split8(f0, f1, ah_, al_);                                       \
    } else {                                                          \
      ah_ = *(const s8v*)(abhi + (size_t)(i) * astep);                \
      al_ = *(const s8v*)(ablo + (size_t)(i) * astep);                \
    }                                                                 \
  }
  // order matches v2 per-accumulator sequence: ah*wh, ah*wl, al*wh (lo*lo dropped)
#define MM3_(wh_, wl_, ah_, al_)                                          \
  {                                                                       \
    acc = __builtin_amdgcn_mfma_f32_32x32x16_bf16(ah_, wh_, acc, 0, 0, 0);\
    acc = __builtin_amdgcn_mfma_f32_32x32x16_bf16(ah_, wl_, acc, 0, 0, 0);\
    acc = __builtin_amdgcn_mfma_f32_32x32x16_bf16(al_, wh_, acc, 0, 0, 0);\
  }

  LOADS_(0, w0h, w0l, a0h, a0l);
  LOADS_(1, w1h, w1l, a1h, a1l);
  LOADS_(2, w2h, w2l, a2h, a2l);
#pragma unroll 1
  for (int kp = 0; kp < 10; ++kp) {
    int i = kp * 3;
    MM3_(w0h, w0l, a0h, a0l);
    LOADS_(i + 3, w0h, w0l, a0h, a0l);          // max 30
    MM3_(w1h, w1l, a1h, a1l);
    LOADS_(i + 4, w1h, w1l, a1h, a1l);          // max 31
    MM3_(w2h, w2l, a2h, a2l);
    if (kp < 9) LOADS_(i + 5, w2h, w2l, a2h, a2l);  // max 29
  }
  MM3_(w0h, w0l, a0h, a0l);  // kt 30
  MM3_(w1h, w1l, a1h, a1l);  // kt 31
#undef LOADS_
#undef MM3_

  // deposit K-half partials (lane-stride-1: conflict-free)
#pragma unroll
  for (int r = 0; r < 16; ++r) {
    int row = (r & 3) + 8 * (r >> 2) + 4 * lh;
    comb[kqh][nt][row][l31] = acc[r];
  }
  __syncthreads();

  // epilogue: 512 threads x 2 cells over the 32x32 tile
  int col = tid & 31;  // == l31 pattern used for bias[]
  int r0 = tid >> 5;   // 0..15
#pragma unroll
  for (int j = 0; j < 2; ++j) {
    int row = r0 + j * 16;
    float g[4];
#pragma unroll
    for (int q = 0; q < 4; ++q)
      g[q] = (comb[0][q][row][col] + comb[1][q][row][col]) + bias[q];
    int brow = b0 + row;
    int hcol = ng * 32 + col;
    size_t coff = (size_t)brow * H + hcol;
    float cp = cbuf[coff];
    float cn = sigf(g[1]) * cp + sigf(g[0]) * tanhfast(g[2]);
    float hn = sigf(g[3]) * tanhfast(cn);
    cbuf[coff] = cn;
    size_t o = ((((size_t)layer * 2 + (step & 1)) * 32 + (hcol >> 4)) * H + brow) * 16 +
               (hcol & 15);
    unsigned ub = __float_as_uint(hn);
    hFhi[o] = (short)(ub >> 16);
    hFlo[o] = (short)bf16_rne(hn - __uint_as_float(ub & 0xffff0000u));
    if (layer) planes[(size_t)step * BH + (size_t)brow * H + hcol] = hn;  // hsq
  }
}

// ---- Kernel 4: conv, hs planes are [t][b][h] ----
__global__ __launch_bounds__(256) void k_conv(
    const float* __restrict__ hs, const float* __restrict__ cW,
    const float* __restrict__ cb, float* __restrict__ feat) {
  int b = blockIdx.x >> 2;
  int h0 = (blockIdx.x & 3) * 128;
  int tid = threadIdx.x;
  __shared__ float sW[TM1][FN];
  for (int i = tid; i < TM1 * FN; i += 256) sW[i >> 5][i & 31] = cW[(i & 31) * TM1 + (i >> 5)];
  __syncthreads();
  int hl = tid & 127, fg = (tid >> 7) * 16;
  float acc[16];
#pragma unroll
  for (int j = 0; j < 16; ++j) acc[j] = cb[fg + j];
  const float* hp = hs + (size_t)b * H + h0 + hl;
  for (int t = 0; t < TM1; ++t) {
    float v = fmaxf(hp[(size_t)t * BH], 0.f);
#pragma unroll
    for (int j = 0; j < 16; ++j) acc[j] = fmaf(v, sW[t][fg + j], acc[j]);
  }
#pragma unroll
  for (int j = 0; j < 16; ++j)
    feat[(size_t)b * (FN * H) + (size_t)(fg + j) * H + h0 + hl] = fmaxf(acc[j], 0.f);
}

// ---- Kernel 5: attention + head; htt = plane T-1 ----
__global__ __launch_bounds__(256) void k_attn(
    const float* __restrict__ hs, const float* __restrict__ feat,
    const float* __restrict__ W1, const float* __restrict__ b1,
    const float* __restrict__ W2, const float* __restrict__ b2,
    const float* __restrict__ Wout, const float* __restrict__ bout,
    float* __restrict__ out) {
  int b = blockIdx.x, tid = threadIdx.x;
  __shared__ float sh[H], sa[H], snew[H], sw[FN], sv[FN], red[256];
  const float* htt = hs + (size_t)(T - 1) * BH + (size_t)b * H;
  for (int i = tid; i < H; i += 256) sh[i] = htt[i];
  __syncthreads();
  {
    int f = tid >> 3, sl = tid & 7;
    const float* w1 = W1 + (size_t)f * H;
    float p = 0.f;
    for (int k = sl * 64; k < sl * 64 + 64; ++k) p = fmaf(sh[k], w1[k], p);
    p += __shfl_xor(p, 1); p += __shfl_xor(p, 2); p += __shfl_xor(p, 4);
    if (sl == 0) sw[f] = p + b1[f];
  }
  __syncthreads();
  const float* fb = feat + (size_t)b * (FN * H);
  for (int i = tid; i < H; i += 256) {
    const float* fr = fb + (size_t)i * FN;
    float p = 0.f;
#pragma unroll
    for (int j = 0; j < FN; j += 4) {
      float4 fv = *(const float4*)(fr + j);
      p = fmaf(fv.x, sw[j], p);
      p = fmaf(fv.y, sw[j + 1], p);
      p = fmaf(fv.z, sw[j + 2], p);
      p = fmaf(fv.w, sw[j + 3], p);
    }
    sa[i] = sigf(p);
  }
  __syncthreads();
  {
    int j = tid & 31, isl = tid >> 5;
    float p = 0.f;
    for (int i = isl * 64; i < isl * 64 + 64; ++i) p = fmaf(sa[i], fb[(size_t)i * FN + j], p);
    red[tid] = p;
  }
  __syncthreads();
  if (tid < 128) red[tid] += red[tid + 128];
  __syncthreads();
  if (tid < 64) red[tid] += red[tid + 64];
  __syncthreads();
  if (tid < 32) sv[tid] = red[tid] + red[tid + 32];
  __syncthreads();
  for (int h = tid; h < H; h += 256) {
    const float* w2 = W2 + (size_t)h * KC;
    float p = b2[h];
#pragma unroll 4
    for (int k = 0; k < H; k += 4) {
      float4 wv = *(const float4*)(w2 + k);
      float4 shv = *(const float4*)(sh + k);
      p = fmaf(shv.x, wv.x, p);
      p = fmaf(shv.y, wv.y, p);
      p = fmaf(shv.z, wv.z, p);
      p = fmaf(shv.w, wv.w, p);
    }
#pragma unroll
    for (int j = 0; j < FN; j += 4) {
      float4 wv = *(const float4*)(w2 + H + j);
      p = fmaf(sv[j], wv.x, p);
      p = fmaf(sv[j + 1], wv.y, p);
      p = fmaf(sv[j + 2], wv.z, p);
      p = fmaf(sv[j + 3], wv.w, p);
    }
    snew[h] = p;
  }
  __syncthreads();
  if (tid < NPRED * 8) {
    int p = tid >> 3, sl = tid & 7;
    const float* wo = Wout + (size_t)(T - NPRED + p) * H;
    float sacc = 0.f;
    for (int k = sl * 64; k < sl * 64 + 64; ++k) sacc = fmaf(snew[k], wo[k], sacc);
    sacc += __shfl_xor(sacc, 1); sacc += __shfl_xor(sacc, 2); sacc += __shfl_xor(sacc, 4);
    if (sl == 0) out[(size_t)b * NPRED + p] = sacc + bout[T - NPRED + p];
  }
}

}  // namespace

extern "C" void kernel_launch(void* const* d_in, const int* in_sizes, int n_in,
                              void* d_out, int out_size, void* d_ws, size_t ws_size,
                              hipStream_t stream) {
  const float* x    = (const float*)d_in[0];
  const int*   sid  = (const int*)d_in[1];
  const float* Wh   = (const float*)d_in[2];
  const float* bh   = (const float*)d_in[3];
  const float* emb  = (const float*)d_in[4];
  const float* Wih  = (const float*)d_in[5];
  const float* Whh  = (const float*)d_in[6];
  const float* bih  = (const float*)d_in[7];
  const float* bhh  = (const float*)d_in[8];
  const float* cW   = (const float*)d_in[9];
  const float* cb   = (const float*)d_in[10];
  const float* W1   = (const float*)d_in[11];
  const float* b1   = (const float*)d_in[12];
  const float* W2   = (const float*)d_in[13];
  const float* b2   = (const float*)d_in[14];
  const float* Wout = (const float*)d_in[15];
  const float* bout = (const float*)d_in[16];
  float* out = (float*)d_out;

  // ws: planes (xc, hsq overwrites in place) | WF hi/lo | hF hi/lo | c0,c1 | feat
  constexpr size_t HFE = (size_t)2 * 2 * 32 * H * 16;  // shorts per hF array
  float* planes = (float*)d_ws;
  short* WFhi = (short*)(planes + (size_t)T * BH);
  short* WFlo = WFhi + (size_t)8192 * 512;
  short* hFhi = WFlo + (size_t)8192 * 512;
  short* hFlo = hFhi + HFE;
  float* cst = (float*)(hFlo + HFE);
  float* c0 = cst;
  float* c1 = cst + BH;
  float* feat = c1 + BH;
  size_t need = (size_t)T * BH * 4 + (size_t)8192 * 512 * 2 * 2 + HFE * 2 * 2 +
                2 * (size_t)BH * 4 + (size_t)B * FN * H * 4;
  if (ws_size < need) return;

  // zero initial h states + c states (contiguous region)
  hipMemsetAsync(hFhi, 0, HFE * 2 * 2 + 2 * (size_t)BH * 4, stream);
  k_xc<<<(B * T / 64) * 2, 256, 0, stream>>>(x, sid, Wh, bh, emb, planes);
  k_wswz<<<2048, 256, 0, stream>>>(Wih, Whh, WFhi, WFlo);

  for (int tt = 0; tt <= T; ++tt)
    k_step5<<<512, 512, 0, stream>>>(tt, planes, WFhi, WFlo, hFhi, hFlo, bih, bhh, c0, c1);

  k_conv<<<B * 4, 256, 0, stream>>>(planes, cW, cb, feat);
  k_attn<<<B, 256, 0, stream>>>(planes, feat, W1, b1, W2, b2, Wout, bout, out);
}